// Round 9
// baseline (248.674 us; speedup 1.0000x reference)
//
#include <hip/hip_runtime.h>
#include <math.h>

#define BB 8
#define SS 1024
#define DD 768
#define HH 12
#define DHH 64
#define BSS (BB*SS)          // 8192
#define NQKV 2304            // stacked Q|K|V output columns

typedef _Float16 half8 __attribute__((ext_vector_type(8)));
typedef _Float16 half4 __attribute__((ext_vector_type(4)));
typedef float    f32x4 __attribute__((ext_vector_type(4)));

// Async global->LDS DMA, 16 B/lane. LDS dest = wave-uniform base + lane*16.
__device__ __forceinline__ void glds16(const _Float16* g, _Float16* l)
{
    __builtin_amdgcn_global_load_lds(
        (const __attribute__((address_space(1))) uint32_t*)(g),
        (__attribute__((address_space(3))) uint32_t*)(l),
        16, 0, 0);
}

// ---------------------------------------------------------------------------
// prep: one launch doing x cast (blocks 0..3071) and all 4 weight
// transposes (blocks 3072..3647 = 576 transpose tiles).
// ---------------------------------------------------------------------------
__global__ __launch_bounds__(256)
void prep(const float* __restrict__ x, _Float16* __restrict__ xh,
          const float* __restrict__ Wq, const float* __restrict__ Wk,
          const float* __restrict__ Wv, const float* __restrict__ Wo,
          _Float16* __restrict__ Wt, _Float16* __restrict__ Wot)
{
    const int blk = blockIdx.x;
    const int tid = threadIdx.x;

    if (blk < 3072) {                    // ---- cast x -> f16 ----
        int i = blk * 256 + tid;
        const float4* xp = (const float4*)x + (size_t)i * 2;
        float4 u = xp[0], v = xp[1];
        half8 h = { (_Float16)u.x, (_Float16)u.y, (_Float16)u.z, (_Float16)u.w,
                    (_Float16)v.x, (_Float16)v.y, (_Float16)v.z, (_Float16)v.w };
        ((half8*)xh)[i] = h;
        return;
    }

    // ---- weight transpose: 576 tiles = (12 d0) x (12 n) x (4 z) ----
    __shared__ float T[64][65];
    const int t  = blk - 3072;
    const int z  = t / 144;              // 0..3
    const int r_ = t - z * 144;
    const int d0 = (r_ / 12) * 64;
    const int n_outer = r_ % 12;

    const float* src;
    _Float16* dst;
    int base_mul, row_stride;
    if (z < 3) {
        src = (z == 0) ? Wq : (z == 1) ? Wk : Wv;
        dst = Wt + (size_t)z * DD * DD;
        base_mul = DD * DHH; row_stride = DHH;
    } else {
        src = Wo; dst = Wot;
        base_mul = 64; row_stride = DD;
    }

    const size_t base = (size_t)n_outer * base_mul;
    {
        int dl = tid >> 2, c0 = (tid & 3) * 16;
        const float* p = src + base + (size_t)(d0 + dl) * row_stride + c0;
#pragma unroll
        for (int m = 0; m < 4; ++m) {
            float4 f = *(const float4*)(p + m * 4);
            T[dl][c0 + m*4 + 0] = f.x;
            T[dl][c0 + m*4 + 1] = f.y;
            T[dl][c0 + m*4 + 2] = f.z;
            T[dl][c0 + m*4 + 3] = f.w;
        }
    }
    __syncthreads();
    {
        int e = tid >> 2, c = tid & 3;
        half8 lo, hi;
#pragma unroll
        for (int i = 0; i < 8; ++i) {
            lo[i] = (_Float16)T[c*16 + i][e];
            hi[i] = (_Float16)T[c*16 + 8 + i][e];
        }
        _Float16* q = dst + ((size_t)n_outer * 64 + e) * DD + d0 + c * 16;
        *(half8*)q = lo;
        *(half8*)(q + 8) = hi;
    }
}

// ---------------------------------------------------------------------------
// Stacked QKV GEMM: 128x256 tile (wave-tile 64x128, acc 4x8), BK=32,
// DMA staging + single-barrier double-buffer. 192 staged B/MFMA (vs 256 at
// 128x128) -> total staged bytes 332 MB, DMA-throughput floor ~25 us.
// Unpadded LDS (uniform 8 words/bank on frag reads = conflict-free).
// Epilogue: Q *0.125 folded; V written transposed vt[bh][e][s].
// ---------------------------------------------------------------------------
__global__ __launch_bounds__(256, 2)
void gemm_qkv_stacked(const _Float16* __restrict__ Xh, const _Float16* __restrict__ Wt,
                      const float* __restrict__ bq, const float* __restrict__ bk,
                      const float* __restrict__ bv,
                      _Float16* __restrict__ qo, _Float16* __restrict__ ko,
                      _Float16* __restrict__ vto)
{
    __shared__ _Float16 Ash[2][128][32];
    __shared__ _Float16 Bsh[2][256][32];

    const int b = blockIdx.x;            // 0..575, XCD swizzle
    const int c  = b & 7;
    const int g  = b >> 3;               // 0..71
    const int n_t = g % 9;
    const int m_t = (g / 9) * 8 + c;
    const int m0 = m_t * 128;
    const int n0 = n_t * 256;

    const int tid  = threadIdx.x;
    const int wave = tid >> 6;
    const int lane = tid & 63;
    const int l16  = tid & 15;
    const int quad = (tid >> 4) & 3;
    const int wy = wave >> 1;
    const int wx = wave & 1;

    // DMA sources: wave stages A rows 32w..32w+31 (2 chunks), B rows 64w..64w+63 (4 chunks)
    const _Float16* ap = Xh + (size_t)(m0 + 32 * wave + (lane >> 2)) * DD + (lane & 3) * 8;
    const _Float16* bp = Wt + (size_t)(n0 + 64 * wave + (lane >> 2)) * DD + (lane & 3) * 8;

    f32x4 acc[4][8];
#pragma unroll
    for (int i = 0; i < 4; ++i)
#pragma unroll
        for (int j = 0; j < 8; ++j) acc[i][j] = (f32x4){0.f, 0.f, 0.f, 0.f};

    // prefetch tile 0 -> buffer 0
    glds16(ap, &Ash[0][32 * wave][0]);
    glds16(ap + 16 * DD, &Ash[0][32 * wave + 16][0]);
#pragma unroll
    for (int t = 0; t < 4; ++t)
        glds16(bp + (size_t)(16 * t) * DD, &Bsh[0][64 * wave + 16 * t][0]);

    int cur = 0;
    for (int k0 = 0; k0 < DD; k0 += 32) {
        __syncthreads();                 // buf[cur] DMA done; buf[cur^1] reads done
        if (k0 + 32 < DD) {
            glds16(ap + k0 + 32, &Ash[cur ^ 1][32 * wave][0]);
            glds16(ap + k0 + 32 + 16 * DD, &Ash[cur ^ 1][32 * wave + 16][0]);
#pragma unroll
            for (int t = 0; t < 4; ++t)
                glds16(bp + k0 + 32 + (size_t)(16 * t) * DD,
                       &Bsh[cur ^ 1][64 * wave + 16 * t][0]);
        }

        half8 a[4], bf[8];
#pragma unroll
        for (int i = 0; i < 4; ++i)
            a[i] = *(const half8*)&Ash[cur][wy * 64 + i * 16 + l16][quad * 8];
#pragma unroll
        for (int j = 0; j < 8; ++j)
            bf[j] = *(const half8*)&Bsh[cur][wx * 128 + j * 16 + l16][quad * 8];
#pragma unroll
        for (int i = 0; i < 4; ++i)
#pragma unroll
            for (int j = 0; j < 8; ++j)
                acc[i][j] = __builtin_amdgcn_mfma_f32_16x16x32_f16(a[i], bf[j], acc[i][j], 0, 0, 0);
        cur ^= 1;
    }

    // ---- epilogue (256 divides 768: no Q/K/V straddle per block) ----
    const int w = n0 / 768;              // 0=Q, 1=K, 2=V
    const float* bp_ = (w == 0) ? bq : (w == 1) ? bk : bv;
    const int nb = (n0 - w * 768) + wx * 128;
    const float qscale = (w == 0) ? 0.125f : 1.0f;

#pragma unroll
    for (int i = 0; i < 4; ++i) {
#pragma unroll
        for (int r = 0; r < 4; ++r) {
            int row = m0 + wy * 64 + i * 16 + quad * 4 + r;
            int b_ = row >> 10;
            int s  = row & (SS - 1);
#pragma unroll
            for (int j = 0; j < 8; ++j) {
                int nl = nb + j * 16 + l16;          // h*64 + e
                int h = nl >> 6, e = nl & 63;
                float val = (acc[i][j][r] + bp_[nl]) * qscale;
                if (w == 0)
                    qo[((size_t)(b_ * HH + h) * SS + s) * DHH + e] = (_Float16)val;
                else if (w == 1)
                    ko[((size_t)(b_ * HH + h) * SS + s) * DHH + e] = (_Float16)val;
                else
                    vto[((size_t)(b_ * HH + h) * DHH + e) * SS + s] = (_Float16)val;
            }
        }
    }
}

// ---------------------------------------------------------------------------
// Out-projection GEMM: 128x64 tile (768 blocks), DMA + single-barrier dbuf.
// Wave-tile 64x32 (acc 4x2). fp32 out + bias.
// ---------------------------------------------------------------------------
__global__ __launch_bounds__(256)
void gemm_out_f16(const _Float16* __restrict__ Ah, const _Float16* __restrict__ Bt,
                  const float* __restrict__ bias, float* __restrict__ out)
{
    __shared__ _Float16 Ash[2][128][32];
    __shared__ _Float16 Bsh[2][64][32];

    const int m0 = blockIdx.x * 128;
    const int n0 = blockIdx.y * 64;
    const int tid  = threadIdx.x;
    const int wave = tid >> 6;
    const int lane = tid & 63;
    const int l16  = tid & 15;
    const int quad = (tid >> 4) & 3;
    const int wy = wave >> 1;
    const int wx = wave & 1;

    const _Float16* ap = Ah + (size_t)(m0 + 32 * wave + (lane >> 2)) * DD + (lane & 3) * 8;
    const _Float16* bp = Bt + (size_t)(n0 + 16 * wave + (lane >> 2)) * DD + (lane & 3) * 8;

    f32x4 acc[4][2];
#pragma unroll
    for (int i = 0; i < 4; ++i)
#pragma unroll
        for (int j = 0; j < 2; ++j) acc[i][j] = (f32x4){0.f, 0.f, 0.f, 0.f};

    glds16(ap, &Ash[0][32 * wave][0]);
    glds16(ap + 16 * DD, &Ash[0][32 * wave + 16][0]);
    glds16(bp, &Bsh[0][16 * wave][0]);

    int cur = 0;
    for (int k0 = 0; k0 < DD; k0 += 32) {
        __syncthreads();
        if (k0 + 32 < DD) {
            glds16(ap + k0 + 32, &Ash[cur ^ 1][32 * wave][0]);
            glds16(ap + k0 + 32 + 16 * DD, &Ash[cur ^ 1][32 * wave + 16][0]);
            glds16(bp + k0 + 32, &Bsh[cur ^ 1][16 * wave][0]);
        }

        half8 a[4], bf[2];
#pragma unroll
        for (int i = 0; i < 4; ++i)
            a[i] = *(const half8*)&Ash[cur][wy * 64 + i * 16 + l16][quad * 8];
#pragma unroll
        for (int j = 0; j < 2; ++j)
            bf[j] = *(const half8*)&Bsh[cur][wx * 32 + j * 16 + l16][quad * 8];
#pragma unroll
        for (int i = 0; i < 4; ++i)
#pragma unroll
            for (int j = 0; j < 2; ++j)
                acc[i][j] = __builtin_amdgcn_mfma_f32_16x16x32_f16(a[i], bf[j], acc[i][j], 0, 0, 0);
        cur ^= 1;
    }

#pragma unroll
    for (int i = 0; i < 4; ++i) {
#pragma unroll
        for (int r = 0; r < 4; ++r) {
            int row = m0 + wy * 64 + i * 16 + quad * 4 + r;
#pragma unroll
            for (int j = 0; j < 2; ++j) {
                int col = n0 + wx * 32 + j * 16 + l16;
                out[(size_t)row * DD + col] = acc[i][j][r] + bias[col];
            }
        }
    }
}

// ---------------------------------------------------------------------------
// Flash attention, f16 MFMA. 512 threads = 8 waves, 128 queries/block.
// K/V^T DMA-staged, single-barrier double-buffer. S^T operand order;
// P via per-wave LDS round-trip. Q pre-scaled by 0.125 in QKV epilogue.
// ---------------------------------------------------------------------------
__global__ __launch_bounds__(512)
void attn_f16(const _Float16* __restrict__ qh, const _Float16* __restrict__ kh,
              const _Float16* __restrict__ vt, _Float16* __restrict__ ctxh)
{
    const int bh  = blockIdx.x;
    const int q0  = blockIdx.y * 128;
    const int tid = threadIdx.x;
    const int wave = tid >> 6;          // 0..7
    const int lane = tid & 63;
    const int l16  = tid & 15;
    const int quad = (tid >> 4) & 3;

    __shared__ _Float16 Ks[2][64][64];
    __shared__ _Float16 Vt[2][64][64];   // V^T tile: [e][kk]
    __shared__ _Float16 Pt[8][16][72];   // per-wave P [q][kk]

    const _Float16* qrow = qh + ((size_t)bh * SS + q0 + wave * 16 + l16) * DHH;
    const half8 qlo = *(const half8*)(qrow + quad * 8);
    const half8 qhi = *(const half8*)(qrow + 32 + quad * 8);

    const _Float16* kp = kh + ((size_t)bh * SS + 8 * wave + (lane >> 3)) * DHH + (lane & 7) * 8;
    const _Float16* vp = vt + ((size_t)bh * DHH + 8 * wave + (lane >> 3)) * SS + (lane & 7) * 8;

    f32x4 o[4];
    float lacc = 0.f;
#pragma unroll
    for (int j = 0; j < 4; ++j) o[j] = (f32x4){0.f, 0.f, 0.f, 0.f};

    glds16(kp, &Ks[0][8 * wave][0]);
    glds16(vp, &Vt[0][8 * wave][0]);

    int cur = 0;
    for (int kt = 0; kt < SS; kt += 64) {
        __syncthreads();
        if (kt + 64 < SS) {
            glds16(kp + (size_t)(kt + 64) * DHH, &Ks[cur ^ 1][8 * wave][0]);
            glds16(vp + kt + 64, &Vt[cur ^ 1][8 * wave][0]);
        }

#pragma unroll
        for (int f = 0; f < 4; ++f) {
            half8 klo = *(const half8*)&Ks[cur][f * 16 + l16][quad * 8];
            half8 khi = *(const half8*)&Ks[cur][f * 16 + l16][32 + quad * 8];
            f32x4 z = (f32x4){0.f, 0.f, 0.f, 0.f};
            z = __builtin_amdgcn_mfma_f32_16x16x32_f16(klo, qlo, z, 0, 0, 0);
            z = __builtin_amdgcn_mfma_f32_16x16x32_f16(khi, qhi, z, 0, 0, 0);
            half4 pk;
#pragma unroll
            for (int r = 0; r < 4; ++r) {
                float p = __expf(z[r]);
                lacc += p;
                pk[r] = (_Float16)p;
            }
            *(half4*)&Pt[wave][l16][f * 16 + quad * 4] = pk;
        }

        half8 pl = *(const half8*)&Pt[wave][l16][quad * 8];
        half8 ph = *(const half8*)&Pt[wave][l16][32 + quad * 8];

#pragma unroll
        for (int j = 0; j < 4; ++j) {
            half8 vlo = *(const half8*)&Vt[cur][j * 16 + l16][quad * 8];
            half8 vhi = *(const half8*)&Vt[cur][j * 16 + l16][32 + quad * 8];
            o[j] = __builtin_amdgcn_mfma_f32_16x16x32_f16(pl, vlo, o[j], 0, 0, 0);
            o[j] = __builtin_amdgcn_mfma_f32_16x16x32_f16(ph, vhi, o[j], 0, 0, 0);
        }
        cur ^= 1;
    }

    float lr = lacc;
    lr += __shfl_xor(lr, 16);
    lr += __shfl_xor(lr, 32);

    const int b_ = bh / HH;
    const int h_ = bh % HH;
#pragma unroll
    for (int r = 0; r < 4; ++r) {
        float invl = 1.f / __shfl(lr, quad * 4 + r, 16);
        int s_ = q0 + wave * 16 + quad * 4 + r;
        _Float16* orow = ctxh + ((size_t)(b_ * SS + s_)) * DD + h_ * DHH;
#pragma unroll
        for (int j = 0; j < 4; ++j)
            orow[j * 16 + l16] = (_Float16)(o[j][r] * invl);
    }
}

// ---------------------------------------------------------------------------
extern "C" void kernel_launch(void* const* d_in, const int* in_sizes, int n_in,
                              void* d_out, int out_size, void* d_ws, size_t ws_size,
                              hipStream_t stream)
{
    const float* x  = (const float*)d_in[0];
    const float* Wq = (const float*)d_in[1];
    const float* bq = (const float*)d_in[2];
    const float* Wk = (const float*)d_in[3];
    const float* bk = (const float*)d_in[4];
    const float* Wv = (const float*)d_in[5];
    const float* bv = (const float*)d_in[6];
    const float* Wo = (const float*)d_in[7];
    const float* bo = (const float*)d_in[8];
    float* out = (float*)d_out;

    const size_t xe = (size_t)BSS * DD;          // 6,291,456
    const size_t we = (size_t)DD * DD;           // 589,824
    _Float16* Xh   = (_Float16*)d_ws;
    _Float16* Wt   = Xh  + xe;                   // [2304][768]
    _Float16* Wot  = Wt  + (size_t)3 * we;
    _Float16* qhb  = Wot + we;
    _Float16* khb  = qhb + xe;
    _Float16* vtb  = khb + xe;                   // [bh][e][s]
    _Float16* ctxh = vtb + xe;

    prep<<<3072 + 576, 256, 0, stream>>>(x, Xh, Wq, Wk, Wv, Wo, Wt, Wot);

    gemm_qkv_stacked<<<(BSS / 128) * (NQKV / 256), 256, 0, stream>>>(
        Xh, Wt, bq, bk, bv, qhb, khb, vtb);

    dim3 ag(BB * HH, SS / 128);      // (96, 8) = 768 blocks
    attn_f16<<<ag, 512, 0, stream>>>(qhb, khb, vtb, ctxh);

    dim3 gg(BSS / 128, DD / 64);     // (64, 12) = 768 blocks
    gemm_out_f16<<<gg, 256, 0, stream>>>(ctxh, Wot, bo, out);
}

// Round 10
// 213.721 us; speedup vs baseline: 1.1635x; 1.1635x over previous
//
#include <hip/hip_runtime.h>
#include <math.h>

#define BB 8
#define SS 1024
#define DD 768
#define HH 12
#define DHH 64
#define BSS (BB*SS)          // 8192
#define NQKV 2304            // stacked Q|K|V output columns

typedef _Float16 half8 __attribute__((ext_vector_type(8)));
typedef _Float16 half4 __attribute__((ext_vector_type(4)));
typedef float    f32x4 __attribute__((ext_vector_type(4)));

// Async global->LDS DMA, 16 B/lane. LDS dest = wave-uniform base + lane*16.
__device__ __forceinline__ void glds16(const _Float16* g, _Float16* l)
{
    __builtin_amdgcn_global_load_lds(
        (const __attribute__((address_space(1))) uint32_t*)(g),
        (__attribute__((address_space(3))) uint32_t*)(l),
        16, 0, 0);
}

// ---------------------------------------------------------------------------
// prep: one launch doing x cast (blocks 0..3071) and all 4 weight
// transposes (blocks 3072..3647).
// ---------------------------------------------------------------------------
__global__ __launch_bounds__(256)
void prep(const float* __restrict__ x, _Float16* __restrict__ xh,
          const float* __restrict__ Wq, const float* __restrict__ Wk,
          const float* __restrict__ Wv, const float* __restrict__ Wo,
          _Float16* __restrict__ Wt, _Float16* __restrict__ Wot)
{
    const int blk = blockIdx.x;
    const int tid = threadIdx.x;

    if (blk < 3072) {                    // ---- cast x -> f16 ----
        int i = blk * 256 + tid;
        const float4* xp = (const float4*)x + (size_t)i * 2;
        float4 u = xp[0], v = xp[1];
        half8 h = { (_Float16)u.x, (_Float16)u.y, (_Float16)u.z, (_Float16)u.w,
                    (_Float16)v.x, (_Float16)v.y, (_Float16)v.z, (_Float16)v.w };
        ((half8*)xh)[i] = h;
        return;
    }

    // ---- weight transpose: 576 tiles = (12 d0) x (12 n) x (4 z) ----
    __shared__ float T[64][65];
    const int t  = blk - 3072;
    const int z  = t / 144;              // 0..3
    const int r_ = t - z * 144;
    const int d0 = (r_ / 12) * 64;
    const int n_outer = r_ % 12;

    const float* src;
    _Float16* dst;
    int base_mul, row_stride;
    if (z < 3) {
        src = (z == 0) ? Wq : (z == 1) ? Wk : Wv;
        dst = Wt + (size_t)z * DD * DD;
        base_mul = DD * DHH; row_stride = DHH;
    } else {
        src = Wo; dst = Wot;
        base_mul = 64; row_stride = DD;
    }

    const size_t base = (size_t)n_outer * base_mul;
    {
        int dl = tid >> 2, c0 = (tid & 3) * 16;
        const float* p = src + base + (size_t)(d0 + dl) * row_stride + c0;
#pragma unroll
        for (int m = 0; m < 4; ++m) {
            float4 f = *(const float4*)(p + m * 4);
            T[dl][c0 + m*4 + 0] = f.x;
            T[dl][c0 + m*4 + 1] = f.y;
            T[dl][c0 + m*4 + 2] = f.z;
            T[dl][c0 + m*4 + 3] = f.w;
        }
    }
    __syncthreads();
    {
        int e = tid >> 2, c = tid & 3;
        half8 lo, hi;
#pragma unroll
        for (int i = 0; i < 8; ++i) {
            lo[i] = (_Float16)T[c*16 + i][e];
            hi[i] = (_Float16)T[c*16 + 8 + i][e];
        }
        _Float16* q = dst + ((size_t)n_outer * 64 + e) * DD + d0 + c * 16;
        *(half8*)q = lo;
        *(half8*)(q + 8) = hi;
    }
}

// ---------------------------------------------------------------------------
// Stacked QKV GEMM (round-8 config): 128x128 tile, BK=32, DMA staging,
// single-barrier double-buffer. Unpadded [128][32] LDS (uniform 8 words/bank).
// Epilogue: Q *0.125 folded; V written transposed vt[bh][e][s].
// ---------------------------------------------------------------------------
__global__ __launch_bounds__(256)
void gemm_qkv_stacked(const _Float16* __restrict__ Xh, const _Float16* __restrict__ Wt,
                      const float* __restrict__ bq, const float* __restrict__ bk,
                      const float* __restrict__ bv,
                      _Float16* __restrict__ qo, _Float16* __restrict__ ko,
                      _Float16* __restrict__ vto)
{
    __shared__ _Float16 Ash[2][128][32];
    __shared__ _Float16 Bsh[2][128][32];

    const int b = blockIdx.x;            // 0..1151, XCD swizzle
    const int c  = b & 7;
    const int g  = b >> 3;
    const int n_t = g % 18;
    const int m_t = (g / 18) * 8 + c;
    const int m0 = m_t * 128;
    const int n0 = n_t * 128;

    const int tid  = threadIdx.x;
    const int wave = tid >> 6;
    const int lane = tid & 63;
    const int l16  = tid & 15;
    const int quad = (tid >> 4) & 3;
    const int wy = wave >> 1;
    const int wx = wave & 1;

    const _Float16* ap = Xh + (size_t)(m0 + 32 * wave + (lane >> 2)) * DD + (lane & 3) * 8;
    const _Float16* bp = Wt + (size_t)(n0 + 32 * wave + (lane >> 2)) * DD + (lane & 3) * 8;

    f32x4 acc[4][4];
#pragma unroll
    for (int i = 0; i < 4; ++i)
#pragma unroll
        for (int j = 0; j < 4; ++j) acc[i][j] = (f32x4){0.f, 0.f, 0.f, 0.f};

    glds16(ap, &Ash[0][32 * wave][0]);
    glds16(ap + 16 * DD, &Ash[0][32 * wave + 16][0]);
    glds16(bp, &Bsh[0][32 * wave][0]);
    glds16(bp + 16 * DD, &Bsh[0][32 * wave + 16][0]);

    int cur = 0;
    for (int k0 = 0; k0 < DD; k0 += 32) {
        __syncthreads();                 // buf[cur] DMA done; buf[cur^1] reads done
        if (k0 + 32 < DD) {
            glds16(ap + k0 + 32, &Ash[cur ^ 1][32 * wave][0]);
            glds16(ap + k0 + 32 + 16 * DD, &Ash[cur ^ 1][32 * wave + 16][0]);
            glds16(bp + k0 + 32, &Bsh[cur ^ 1][32 * wave][0]);
            glds16(bp + k0 + 32 + 16 * DD, &Bsh[cur ^ 1][32 * wave + 16][0]);
        }

        half8 a[4], bf[4];
#pragma unroll
        for (int i = 0; i < 4; ++i)
            a[i] = *(const half8*)&Ash[cur][wy * 64 + i * 16 + l16][quad * 8];
#pragma unroll
        for (int j = 0; j < 4; ++j)
            bf[j] = *(const half8*)&Bsh[cur][wx * 64 + j * 16 + l16][quad * 8];
#pragma unroll
        for (int i = 0; i < 4; ++i)
#pragma unroll
            for (int j = 0; j < 4; ++j)
                acc[i][j] = __builtin_amdgcn_mfma_f32_16x16x32_f16(a[i], bf[j], acc[i][j], 0, 0, 0);
        cur ^= 1;
    }

    // ---- epilogue ----
    const int w = n0 / 768;              // 0=Q, 1=K, 2=V
    const float* bp_ = (w == 0) ? bq : (w == 1) ? bk : bv;
    const int nb = n0 - w * 768 + wx * 64;
    const float qscale = (w == 0) ? 0.125f : 1.0f;

#pragma unroll
    for (int i = 0; i < 4; ++i) {
#pragma unroll
        for (int r = 0; r < 4; ++r) {
            int row = m0 + wy * 64 + i * 16 + quad * 4 + r;
            int b_ = row >> 10;
            int s  = row & (SS - 1);
#pragma unroll
            for (int j = 0; j < 4; ++j) {
                int nl = nb + j * 16 + l16;          // h*64 + e
                int h = nl >> 6, e = nl & 63;
                float val = (acc[i][j][r] + bp_[nl]) * qscale;
                if (w == 0)
                    qo[((size_t)(b_ * HH + h) * SS + s) * DHH + e] = (_Float16)val;
                else if (w == 1)
                    ko[((size_t)(b_ * HH + h) * SS + s) * DHH + e] = (_Float16)val;
                else
                    vto[((size_t)(b_ * HH + h) * DHH + e) * SS + s] = (_Float16)val;
            }
        }
    }
}

// ---------------------------------------------------------------------------
// Out-projection GEMM (round-8 config): 128x64 tile, DMA + single-barrier
// dbuf, wave-tile 64x32. fp32 out + bias.
// ---------------------------------------------------------------------------
__global__ __launch_bounds__(256)
void gemm_out_f16(const _Float16* __restrict__ Ah, const _Float16* __restrict__ Bt,
                  const float* __restrict__ bias, float* __restrict__ out)
{
    __shared__ _Float16 Ash[2][128][32];
    __shared__ _Float16 Bsh[2][64][32];

    const int m0 = blockIdx.x * 128;
    const int n0 = blockIdx.y * 64;
    const int tid  = threadIdx.x;
    const int wave = tid >> 6;
    const int lane = tid & 63;
    const int l16  = tid & 15;
    const int quad = (tid >> 4) & 3;
    const int wy = wave >> 1;
    const int wx = wave & 1;

    const _Float16* ap = Ah + (size_t)(m0 + 32 * wave + (lane >> 2)) * DD + (lane & 3) * 8;
    const _Float16* bp = Bt + (size_t)(n0 + 16 * wave + (lane >> 2)) * DD + (lane & 3) * 8;

    f32x4 acc[4][2];
#pragma unroll
    for (int i = 0; i < 4; ++i)
#pragma unroll
        for (int j = 0; j < 2; ++j) acc[i][j] = (f32x4){0.f, 0.f, 0.f, 0.f};

    glds16(ap, &Ash[0][32 * wave][0]);
    glds16(ap + 16 * DD, &Ash[0][32 * wave + 16][0]);
    glds16(bp, &Bsh[0][16 * wave][0]);

    int cur = 0;
    for (int k0 = 0; k0 < DD; k0 += 32) {
        __syncthreads();
        if (k0 + 32 < DD) {
            glds16(ap + k0 + 32, &Ash[cur ^ 1][32 * wave][0]);
            glds16(ap + k0 + 32 + 16 * DD, &Ash[cur ^ 1][32 * wave + 16][0]);
            glds16(bp + k0 + 32, &Bsh[cur ^ 1][16 * wave][0]);
        }

        half8 a[4], bf[2];
#pragma unroll
        for (int i = 0; i < 4; ++i)
            a[i] = *(const half8*)&Ash[cur][wy * 64 + i * 16 + l16][quad * 8];
#pragma unroll
        for (int j = 0; j < 2; ++j)
            bf[j] = *(const half8*)&Bsh[cur][wx * 32 + j * 16 + l16][quad * 8];
#pragma unroll
        for (int i = 0; i < 4; ++i)
#pragma unroll
            for (int j = 0; j < 2; ++j)
                acc[i][j] = __builtin_amdgcn_mfma_f32_16x16x32_f16(a[i], bf[j], acc[i][j], 0, 0, 0);
        cur ^= 1;
    }

#pragma unroll
    for (int i = 0; i < 4; ++i) {
#pragma unroll
        for (int r = 0; r < 4; ++r) {
            int row = m0 + wy * 64 + i * 16 + quad * 4 + r;
#pragma unroll
            for (int j = 0; j < 2; ++j) {
                int col = n0 + wx * 32 + j * 16 + l16;
                out[(size_t)row * DD + col] = acc[i][j][r] + bias[col];
            }
        }
    }
}

// ---------------------------------------------------------------------------
// Flash attention, f16 MFMA, 512 thr / 128 q. CONFLICT-FREE LDS:
// K and V^T stored chunked [c][64][32] (c = 32-half chunk of the inner dim)
// so frag-read row stride = 16 words -> uniform 8 words/bank (was [64][64]:
// 32-word stride -> all quad lanes on same 4 banks = 16-way conflict).
// Waves 0-3 stage K (2 chunk-planes each), waves 4-7 stage V^T.
// Single-barrier dbuf; S^T operand order; P via per-wave LDS round-trip.
// ---------------------------------------------------------------------------
__global__ __launch_bounds__(512)
void attn_f16(const _Float16* __restrict__ qh, const _Float16* __restrict__ kh,
              const _Float16* __restrict__ vt, _Float16* __restrict__ ctxh)
{
    const int bh  = blockIdx.x;
    const int q0  = blockIdx.y * 128;
    const int tid = threadIdx.x;
    const int wave = tid >> 6;          // 0..7
    const int lane = tid & 63;
    const int l16  = tid & 15;
    const int quad = (tid >> 4) & 3;

    __shared__ _Float16 Ks[2][2][64][32];   // [dbuf][d-chunk][key][32]
    __shared__ _Float16 Vt[2][2][64][32];   // [dbuf][kk-chunk][e][32]
    __shared__ _Float16 Pt[8][16][72];      // per-wave P [q][kk]

    // ---- Q frags: direct global (once) ----
    const _Float16* qrow = qh + ((size_t)bh * SS + q0 + wave * 16 + l16) * DHH;
    const half8 qlo = *(const half8*)(qrow + quad * 8);
    const half8 qhi = *(const half8*)(qrow + 32 + quad * 8);

    // ---- DMA sources: sub-wave sw covers 16 rows of its matrix ----
    const int sw = wave & 3;
    // K: lane i -> row 16sw + (i>>2), d = (i&3)*8 (+32 for chunk 1)
    const _Float16* kp = kh + ((size_t)bh * SS + 16 * sw + (lane >> 2)) * DHH + (lane & 3) * 8;
    // V^T: lane i -> e-row 16sw + (i>>2), s-col = kt + c*32 + (i&3)*8
    const _Float16* vp = vt + ((size_t)bh * DHH + 16 * sw + (lane >> 2)) * SS + (lane & 3) * 8;

    f32x4 o[4];
    float lacc = 0.f;
#pragma unroll
    for (int j = 0; j < 4; ++j) o[j] = (f32x4){0.f, 0.f, 0.f, 0.f};

    // ---- prefetch tile 0 -> buffer 0 ----
    if (wave < 4) {
        glds16(kp,      &Ks[0][0][16 * sw][0]);
        glds16(kp + 32, &Ks[0][1][16 * sw][0]);
    } else {
        glds16(vp,      &Vt[0][0][16 * sw][0]);
        glds16(vp + 32, &Vt[0][1][16 * sw][0]);
    }

    int cur = 0;
    for (int kt = 0; kt < SS; kt += 64) {
        __syncthreads();                 // buf[cur] ready; buf[cur^1] reads done
        if (kt + 64 < SS) {
            if (wave < 4) {
                glds16(kp + (size_t)(kt + 64) * DHH,      &Ks[cur ^ 1][0][16 * sw][0]);
                glds16(kp + (size_t)(kt + 64) * DHH + 32, &Ks[cur ^ 1][1][16 * sw][0]);
            } else {
                glds16(vp + kt + 64,      &Vt[cur ^ 1][0][16 * sw][0]);
                glds16(vp + kt + 64 + 32, &Vt[cur ^ 1][1][16 * sw][0]);
            }
        }

        // ---- S^T = K·Q^T per 16-kk tile; exp; vectorized P write ----
#pragma unroll
        for (int f = 0; f < 4; ++f) {
            half8 klo = *(const half8*)&Ks[cur][0][f * 16 + l16][quad * 8];
            half8 khi = *(const half8*)&Ks[cur][1][f * 16 + l16][quad * 8];
            f32x4 z = (f32x4){0.f, 0.f, 0.f, 0.f};
            z = __builtin_amdgcn_mfma_f32_16x16x32_f16(klo, qlo, z, 0, 0, 0);
            z = __builtin_amdgcn_mfma_f32_16x16x32_f16(khi, qhi, z, 0, 0, 0);
            half4 pk;
#pragma unroll
            for (int r = 0; r < 4; ++r) {
                float p = __expf(z[r]);
                lacc += p;
                pk[r] = (_Float16)p;
            }
            *(half4*)&Pt[wave][l16][f * 16 + quad * 4] = pk;
        }

        // ---- P A-frags (same-wave LDS round trip, in-order DS) ----
        half8 pl = *(const half8*)&Pt[wave][l16][quad * 8];
        half8 ph = *(const half8*)&Pt[wave][l16][32 + quad * 8];

        // ---- PV ----
#pragma unroll
        for (int j = 0; j < 4; ++j) {
            half8 vlo = *(const half8*)&Vt[cur][0][j * 16 + l16][quad * 8];
            half8 vhi = *(const half8*)&Vt[cur][1][j * 16 + l16][quad * 8];
            o[j] = __builtin_amdgcn_mfma_f32_16x16x32_f16(pl, vlo, o[j], 0, 0, 0);
            o[j] = __builtin_amdgcn_mfma_f32_16x16x32_f16(ph, vhi, o[j], 0, 0, 0);
        }
        cur ^= 1;
    }

    // ---- l: sum quad partials (same q = l16 across quads) ----
    float lr = lacc;
    lr += __shfl_xor(lr, 16);
    lr += __shfl_xor(lr, 32);

    const int b_ = bh / HH;
    const int h_ = bh % HH;
#pragma unroll
    for (int r = 0; r < 4; ++r) {
        float invl = 1.f / __shfl(lr, quad * 4 + r, 16);
        int s_ = q0 + wave * 16 + quad * 4 + r;
        _Float16* orow = ctxh + ((size_t)(b_ * SS + s_)) * DD + h_ * DHH;
#pragma unroll
        for (int j = 0; j < 4; ++j)
            orow[j * 16 + l16] = (_Float16)(o[j][r] * invl);
    }
}

// ---------------------------------------------------------------------------
extern "C" void kernel_launch(void* const* d_in, const int* in_sizes, int n_in,
                              void* d_out, int out_size, void* d_ws, size_t ws_size,
                              hipStream_t stream)
{
    const float* x  = (const float*)d_in[0];
    const float* Wq = (const float*)d_in[1];
    const float* bq = (const float*)d_in[2];
    const float* Wk = (const float*)d_in[3];
    const float* bk = (const float*)d_in[4];
    const float* Wv = (const float*)d_in[5];
    const float* bv = (const float*)d_in[6];
    const float* Wo = (const float*)d_in[7];
    const float* bo = (const float*)d_in[8];
    float* out = (float*)d_out;

    const size_t xe = (size_t)BSS * DD;          // 6,291,456
    const size_t we = (size_t)DD * DD;           // 589,824
    _Float16* Xh   = (_Float16*)d_ws;
    _Float16* Wt   = Xh  + xe;                   // [2304][768]
    _Float16* Wot  = Wt  + (size_t)3 * we;
    _Float16* qhb  = Wot + we;
    _Float16* khb  = qhb + xe;
    _Float16* vtb  = khb + xe;                   // [bh][e][s]
    _Float16* ctxh = vtb + xe;

    prep<<<3072 + 576, 256, 0, stream>>>(x, Xh, Wq, Wk, Wv, Wo, Wt, Wot);

    gemm_qkv_stacked<<<(BSS / 128) * (NQKV / 128), 256, 0, stream>>>(
        Xh, Wt, bq, bk, bv, qhb, khb, vtb);

    dim3 ag(BB * HH, SS / 128);      // (96, 8) = 768 blocks
    attn_f16<<<ag, 512, 0, stream>>>(qhb, khb, vtb, ctxh);

    dim3 gg(BSS / 128, DD / 64);     // (64, 12) = 768 blocks
    gemm_out_f16<<<gg, 256, 0, stream>>>(ctxh, Wot, bo, out);
}